// Round 4
// baseline (489.486 us; speedup 1.0000x reference)
//
#include <hip/hip_runtime.h>

#define BLOCK 256
#define GRID 2048
#define NWAVES (BLOCK / 64)

typedef float f32x4 __attribute__((ext_vector_type(4)));
typedef int i32x4 __attribute__((ext_vector_type(4)));

// per-element BCE-with-logits: max(x,0) - x*t + log(1 + exp(-|x|))
// == softplus(x) for t=0, softplus(-x) for t=1  (matches -where(t==0, -sp(x), -sp(-x)))
__device__ __forceinline__ float bce_elem(float x, int t) {
    float tf = (t != 0) ? 1.0f : 0.0f;
    float ax = fabsf(x);
    float e = __expf(-ax);
    return fmaxf(x, 0.0f) - x * tf + __logf(1.0f + e);
}

__device__ __forceinline__ float bce_quad(f32x4 xv, i32x4 tv) {
    return bce_elem(xv.x, tv.x) + bce_elem(xv.y, tv.y) +
           bce_elem(xv.z, tv.z) + bce_elem(xv.w, tv.w);
}

__global__ __launch_bounds__(BLOCK) void bce_partial_kernel(
    const float* __restrict__ x, const int* __restrict__ t,
    float* __restrict__ partial, int n4) {
    const f32x4* __restrict__ x4 = (const f32x4*)x;
    const i32x4* __restrict__ t4 = (const i32x4*)t;

    float acc = 0.0f;
    const int stride = gridDim.x * blockDim.x;
    int i = blockIdx.x * blockDim.x + threadIdx.x;

    // unroll-4: 8 outstanding nontemporal 16B loads issued back-to-back
    // before any dependent compute — maximize MLP per wave.
    for (; i + 3 * stride < n4; i += 4 * stride) {
        f32x4 xa = __builtin_nontemporal_load(&x4[i]);
        f32x4 xb = __builtin_nontemporal_load(&x4[i + stride]);
        f32x4 xc = __builtin_nontemporal_load(&x4[i + 2 * stride]);
        f32x4 xd = __builtin_nontemporal_load(&x4[i + 3 * stride]);
        i32x4 ta = __builtin_nontemporal_load(&t4[i]);
        i32x4 tb = __builtin_nontemporal_load(&t4[i + stride]);
        i32x4 tc = __builtin_nontemporal_load(&t4[i + 2 * stride]);
        i32x4 td = __builtin_nontemporal_load(&t4[i + 3 * stride]);
        acc += bce_quad(xa, ta);
        acc += bce_quad(xb, tb);
        acc += bce_quad(xc, tc);
        acc += bce_quad(xd, td);
    }
    for (; i < n4; i += stride) {
        f32x4 xa = __builtin_nontemporal_load(&x4[i]);
        i32x4 ta = __builtin_nontemporal_load(&t4[i]);
        acc += bce_quad(xa, ta);
    }

    // wave-64 reduction
    #pragma unroll
    for (int off = 32; off > 0; off >>= 1)
        acc += __shfl_down(acc, off, 64);

    __shared__ float wsum[NWAVES];
    const int lane = threadIdx.x & 63;
    const int wave = threadIdx.x >> 6;
    if (lane == 0) wsum[wave] = acc;
    __syncthreads();
    if (threadIdx.x == 0) {
        float s = 0.0f;
        #pragma unroll
        for (int w = 0; w < NWAVES; w++) s += wsum[w];
        partial[blockIdx.x] = s;
    }
}

__global__ __launch_bounds__(BLOCK) void bce_final_kernel(
    const float* __restrict__ partial, float* __restrict__ out,
    int n_partial, double inv_n) {
    double acc = 0.0;
    for (int i = threadIdx.x; i < n_partial; i += BLOCK)
        acc += (double)partial[i];

    #pragma unroll
    for (int off = 32; off > 0; off >>= 1)
        acc += __shfl_down(acc, off, 64);

    __shared__ double wsum[NWAVES];
    const int lane = threadIdx.x & 63;
    const int wave = threadIdx.x >> 6;
    if (lane == 0) wsum[wave] = acc;
    __syncthreads();
    if (threadIdx.x == 0) {
        double s = 0.0;
        #pragma unroll
        for (int w = 0; w < NWAVES; w++) s += wsum[w];
        out[0] = (float)(s * inv_n);
    }
}

extern "C" void kernel_launch(void* const* d_in, const int* in_sizes, int n_in,
                              void* d_out, int out_size, void* d_ws, size_t ws_size,
                              hipStream_t stream) {
    const float* x = (const float*)d_in[0];
    const int* t = (const int*)d_in[1];
    float* out = (float*)d_out;
    float* partial = (float*)d_ws;  // GRID floats of scratch

    const long long n = (long long)in_sizes[0];  // 8192*8192 = 67108864, divisible by 4
    const int n4 = (int)(n / 4);

    bce_partial_kernel<<<GRID, BLOCK, 0, stream>>>(x, t, partial, n4);
    bce_final_kernel<<<1, BLOCK, 0, stream>>>(partial, out, GRID, 1.0 / (double)n);
}

// Round 5
// 472.863 us; speedup vs baseline: 1.0352x; 1.0352x over previous
//
#include <hip/hip_runtime.h>

#define BLOCK 256
#define GRID 2048
#define NWAVES (BLOCK / 64)

typedef float f32x4 __attribute__((ext_vector_type(4)));
typedef int i32x4 __attribute__((ext_vector_type(4)));

// per-element BCE-with-logits: max(x,0) - x*t + log(1 + exp(-|x|))
// == softplus(x) for t=0, softplus(-x) for t=1  (matches -where(t==0, -sp(x), -sp(-x)))
__device__ __forceinline__ float bce_elem(float x, int t) {
    float tf = (t != 0) ? 1.0f : 0.0f;
    float ax = fabsf(x);
    float e = __expf(-ax);
    return fmaxf(x, 0.0f) - x * tf + __logf(1.0f + e);
}

__device__ __forceinline__ float bce_quad(f32x4 xv, i32x4 tv) {
    return bce_elem(xv.x, tv.x) + bce_elem(xv.y, tv.y) +
           bce_elem(xv.z, tv.z) + bce_elem(xv.w, tv.w);
}

__global__ __launch_bounds__(BLOCK) void bce_partial_kernel(
    const float* __restrict__ x, const int* __restrict__ t,
    float* __restrict__ partial, int n4) {
    const f32x4* __restrict__ x4 = (const f32x4*)x;
    const i32x4* __restrict__ t4 = (const i32x4*)t;

    // Blocked layout: each block owns a contiguous chunk of iters*BLOCK float4s.
    // Within the chunk, accesses are block-cyclic (coalesced 1KB lines per wave,
    // sequential within a 128KB window -> good DRAM page locality).
    const int iters = n4 / (GRID * BLOCK);   // 32 for n=8192^2
    const int chunk = iters * BLOCK;

    float acc = 0.0f;
    int idx = blockIdx.x * chunk + threadIdx.x;

    if (iters > 0) {
        // software pipeline depth 1: compute on (xa,ta) overlaps next loads
        f32x4 xa = __builtin_nontemporal_load(&x4[idx]);
        i32x4 ta = __builtin_nontemporal_load(&t4[idx]);
        for (int k = 1; k < iters; k++) {
            const int j = idx + k * BLOCK;
            f32x4 xb = __builtin_nontemporal_load(&x4[j]);
            i32x4 tb = __builtin_nontemporal_load(&t4[j]);
            acc += bce_quad(xa, ta);
            xa = xb;
            ta = tb;
        }
        acc += bce_quad(xa, ta);
    }

    // tail: elements [GRID*chunk, n4) via grid-stride (empty when divisible)
    for (int j = GRID * chunk + blockIdx.x * BLOCK + threadIdx.x; j < n4;
         j += GRID * BLOCK) {
        f32x4 xa = __builtin_nontemporal_load(&x4[j]);
        i32x4 ta = __builtin_nontemporal_load(&t4[j]);
        acc += bce_quad(xa, ta);
    }

    // wave-64 reduction
    #pragma unroll
    for (int off = 32; off > 0; off >>= 1)
        acc += __shfl_down(acc, off, 64);

    __shared__ float wsum[NWAVES];
    const int lane = threadIdx.x & 63;
    const int wave = threadIdx.x >> 6;
    if (lane == 0) wsum[wave] = acc;
    __syncthreads();
    if (threadIdx.x == 0) {
        float s = 0.0f;
        #pragma unroll
        for (int w = 0; w < NWAVES; w++) s += wsum[w];
        partial[blockIdx.x] = s;
    }
}

__global__ __launch_bounds__(BLOCK) void bce_final_kernel(
    const float* __restrict__ partial, float* __restrict__ out,
    int n_partial, double inv_n) {
    double acc = 0.0;
    for (int i = threadIdx.x; i < n_partial; i += BLOCK)
        acc += (double)partial[i];

    #pragma unroll
    for (int off = 32; off > 0; off >>= 1)
        acc += __shfl_down(acc, off, 64);

    __shared__ double wsum[NWAVES];
    const int lane = threadIdx.x & 63;
    const int wave = threadIdx.x >> 6;
    if (lane == 0) wsum[wave] = acc;
    __syncthreads();
    if (threadIdx.x == 0) {
        double s = 0.0;
        #pragma unroll
        for (int w = 0; w < NWAVES; w++) s += wsum[w];
        out[0] = (float)(s * inv_n);
    }
}

extern "C" void kernel_launch(void* const* d_in, const int* in_sizes, int n_in,
                              void* d_out, int out_size, void* d_ws, size_t ws_size,
                              hipStream_t stream) {
    const float* x = (const float*)d_in[0];
    const int* t = (const int*)d_in[1];
    float* out = (float*)d_out;
    float* partial = (float*)d_ws;  // GRID floats of scratch

    const long long n = (long long)in_sizes[0];  // 8192*8192 = 67108864, divisible by 4
    const int n4 = (int)(n / 4);

    bce_partial_kernel<<<GRID, BLOCK, 0, stream>>>(x, t, partial, n4);
    bce_final_kernel<<<1, BLOCK, 0, stream>>>(partial, out, GRID, 1.0 / (double)n);
}